// Round 11
// baseline (321.882 us; speedup 1.0000x reference)
//
#include <hip/hip_runtime.h>
#include <hip/hip_bf16.h>

// CrossAttention: B=4, C=256, N=4096, OUT=256, temp=16.
// v11: LDS-traffic cut in flash: V via REGISTER prefetch (global b128, one
// interval of flight), K via dma16 LDS dbuf (r8 path), 512-thr 4P+4C.
// Main loop unrolled x2 so vreg[] indices are compile-time (no scratch).
// Per-interval LDS 232KB -> 104KB (~matches 1080cyc MFMA wall).
// proj: r10 verbatim (2-kernel structure kept; residual ~105us suspected
// fixed harness cost - this round's flash speedup discriminates).

typedef __attribute__((ext_vector_type(8))) short bf16x8;
typedef __attribute__((ext_vector_type(4))) float f32x4;
typedef __attribute__((ext_vector_type(4))) short short4t;

constexpr int B_ = 4;
constexpr int C_ = 256;
constexpr int N_ = 4096;
constexpr int O_ = 256;
constexpr float INV_TEMP = 1.0f / 16.0f;
constexpr int NIT = 64;   // 64-key intervals (all 4096 keys, SPLIT=1)

__device__ __forceinline__ short f2bf(float f) {
  union { float f; unsigned u; } v; v.f = f;
  unsigned r = v.u + 0x7fffu + ((v.u >> 16) & 1u);   // RNE
  return (short)(r >> 16);
}

// async global->LDS DMA: lane i reads g + i*16B, lands at ldsbase + i*16B.
__device__ __forceinline__ void dma16(const void* g, void* l) {
  __builtin_amdgcn_global_load_lds(
      (const __attribute__((address_space(1))) unsigned int*)g,
      (__attribute__((address_space(3))) unsigned int*)l, 16, 0, 0);
}

// ---------------------------------------------------------------------------
// Projections (r10 verbatim). Grid (64, B, 3). Block 256. z: 0=Q, 1=K, 2=V.
// ---------------------------------------------------------------------------
__global__ __launch_bounds__(256, 2) void qkv_proj(
    const float* __restrict__ x, const float* __restrict__ xx,
    const float* __restrict__ Wq, const float* __restrict__ Wk,
    const float* __restrict__ Wv,
    short* __restrict__ qg, short* __restrict__ kt, short* __restrict__ vt) {
  const int n0  = blockIdx.x * 64;
  const int b   = blockIdx.y;
  const int mat = blockIdx.z;
  const float* src = (mat == 0) ? x : xx;
  const float* Wm  = (mat == 0) ? Wq : (mat == 1 ? Wk : Wv);
  const float ws   = (mat == 0) ? INV_TEMP : 1.0f;
  const int tid = threadIdx.x;
  const int w = tid >> 6, lane = tid & 63;
  const int g = lane >> 4, c16 = lane & 15;

  __shared__ __align__(16) short xs[64][264];   // staged tile / out assembly

  {  // transpose staging: coalesced dword loads along n, short4 LDS writes
    const int n = tid & 63, cq = tid >> 6;
    const float* sp = src + (size_t)b * C_ * N_ + n0 + n;
#pragma unroll
    for (int rep = 0; rep < 16; ++rep) {
      int c = rep * 16 + cq * 4;
      short4t s4;
#pragma unroll
      for (int j = 0; j < 4; ++j) s4[j] = f2bf(sp[(size_t)(c + j) * N_]);
      *(short4t*)&xs[n][c] = s4;
    }
  }
  __syncthreads();

  f32x4 acc[4][4];
#pragma unroll
  for (int i = 0; i < 4; ++i)
#pragma unroll
    for (int j = 0; j < 4; ++j) acc[i][j] = (f32x4){0.f, 0.f, 0.f, 0.f};

#pragma unroll
  for (int ko = 0; ko < 8; ++ko) {
    bf16x8 wfr[4], xfr[4];
#pragma unroll
    for (int ot = 0; ot < 4; ++ot) {
      const float* wp =
          Wm + (size_t)(w * 64 + ot * 16 + c16) * C_ + ko * 32 + g * 8;
      float4 f0 = *(const float4*)wp;
      float4 f1 = *(const float4*)(wp + 4);
      bf16x8 a;
      a[0] = f2bf(f0.x * ws); a[1] = f2bf(f0.y * ws);
      a[2] = f2bf(f0.z * ws); a[3] = f2bf(f0.w * ws);
      a[4] = f2bf(f1.x * ws); a[5] = f2bf(f1.y * ws);
      a[6] = f2bf(f1.z * ws); a[7] = f2bf(f1.w * ws);
      wfr[ot] = a;
    }
#pragma unroll
    for (int nt = 0; nt < 4; ++nt)
      xfr[nt] = *(const bf16x8*)&xs[nt * 16 + c16][ko * 32 + g * 8];
    if (mat < 2) {
#pragma unroll
      for (int ot = 0; ot < 4; ++ot)
#pragma unroll
        for (int nt = 0; nt < 4; ++nt)
          acc[ot][nt] = __builtin_amdgcn_mfma_f32_16x16x32_bf16(
              wfr[ot], xfr[nt], acc[ot][nt], 0, 0, 0);
    } else {  // V: swapped operands -> D rows = m, cols = o
#pragma unroll
      for (int mt = 0; mt < 4; ++mt)
#pragma unroll
        for (int ot = 0; ot < 4; ++ot)
          acc[mt][ot] = __builtin_amdgcn_mfma_f32_16x16x32_bf16(
              xfr[mt], wfr[ot], acc[mt][ot], 0, 0, 0);
    }
  }

  __syncthreads();               // xs tile reads done; reuse as out-assembly
  short* ob = &xs[0][0];         // 16384 shorts used

  if (mat == 0) {
#pragma unroll
    for (int ot = 0; ot < 4; ++ot)
#pragma unroll
      for (int nt = 0; nt < 4; ++nt) {
        int f = (nt * 16 + c16) * 256 + w * 64 + ot * 16 + g * 4;
        short4t s;
        s[0] = f2bf(acc[ot][nt][0]);
        s[1] = f2bf(acc[ot][nt][1]);
        s[2] = f2bf(acc[ot][nt][2]);
        s[3] = f2bf(acc[ot][nt][3]);
        *(short4t*)&ob[f] = s;
      }
  } else if (mat == 1) {
#pragma unroll
    for (int ot = 0; ot < 4; ++ot)
#pragma unroll
      for (int nt = 0; nt < 4; ++nt) {
        int koo = w * 2 + (ot >> 1);
        int pos = (((ot & 1) * 2 + (g >> 1)) ^ ((c16 >> 1) & 3));
        int f = nt * 4096 + koo * 512 + c16 * 32 + pos * 8 + (g & 1) * 4;
        short4t s;
        s[0] = f2bf(acc[ot][nt][0]);
        s[1] = f2bf(acc[ot][nt][1]);
        s[2] = f2bf(acc[ot][nt][2]);
        s[3] = f2bf(acc[ot][nt][3]);
        *(short4t*)&ob[f] = s;
      }
  } else {  // V: acc[mt][ot], rows m = mt*16+g*4+r, cols o = w*64+ot*16+c16
#pragma unroll
    for (int mt = 0; mt < 4; ++mt)
#pragma unroll
      for (int ot = 0; ot < 4; ++ot) {
        int o = w * 64 + ot * 16 + c16;
        int pos = (mt * 2 + (g >> 1)) ^ (o & 7);
        int f = o * 64 + pos * 8 + (g & 1) * 4;
        short4t s;
        s[0] = f2bf(acc[mt][ot][0]);
        s[1] = f2bf(acc[mt][ot][1]);
        s[2] = f2bf(acc[mt][ot][2]);
        s[3] = f2bf(acc[mt][ot][3]);
        *(short4t*)&ob[f] = s;
      }
  }
  __syncthreads();

  short* dst = (mat == 0) ? qg + ((size_t)b * N_ + n0) * O_
             : (mat == 1) ? kt + (size_t)(b * 256 + (n0 >> 4)) * 4096
                          : vt + (size_t)(b * 64 + (n0 >> 6)) * 16384;
  const uint4* s4 = (const uint4*)ob;
  uint4* d4 = (uint4*)dst;
#pragma unroll
  for (int j = 0; j < 8; ++j) d4[j * 256 + tid] = s4[j * 256 + tid];
}

// ---------------------------------------------------------------------------
// Flash attention. Grid (8, 32). Block 512 (4 producers + 4 consumers).
// b = x>>1 (XCD-pinned). Producers: K via dma16 LDS dbuf, S for own granule.
// Consumers: V via REGISTER prefetch (8 global b128, one interval of flight),
// PV for own 64-o slice. LDS: kb 64KB + ps 18KB + lsum = 83.5KB.
// ---------------------------------------------------------------------------
#define PSTEP(I, CUR)                                                        \
  if (prod) {                                                                \
    if ((I) < NIT) {                                                         \
      if ((I) + 1 < NIT) { /* prefetch K(I+1) granule pw */                  \
        const short* src = ktb + (size_t)(4 * ((I) + 1) + pw) * 4096;        \
        short* dst = &kb[(CUR) ^ 1][pw * 4096];                              \
        _Pragma("unroll")                                                    \
        for (int j = 0; j < 8; ++j)                                          \
          dma16(src + j * 512 + lane * 8, dst + j * 512);                    \
      }                                                                      \
      const short* ksl = &kb[(CUR)][pw * 4096];                              \
      f32x4 sacc[4];                                                         \
      _Pragma("unroll")                                                      \
      for (int nt = 0; nt < 4; ++nt) sacc[nt] = (f32x4){0.f, 0.f, 0.f, 0.f};\
      _Pragma("unroll")                                                      \
      for (int ko = 0; ko < 8; ++ko) {                                       \
        bf16x8 kf = *(const bf16x8*)&ksl[(ko * 16 + c16) * 32 + sw];         \
        _Pragma("unroll")                                                    \
        for (int nt = 0; nt < 4; ++nt)                                       \
          sacc[nt] = __builtin_amdgcn_mfma_f32_16x16x32_bf16(                \
              kf, qf[nt][ko], sacc[nt], 0, 0, 0);                            \
      }                                                                      \
      _Pragma("unroll")                                                      \
      for (int nt = 0; nt < 4; ++nt) {                                       \
        short4t pb;                                                          \
        float rs = 0.f;                                                      \
        _Pragma("unroll")                                                    \
        for (int r = 0; r < 4; ++r) {                                        \
          float p = __expf(sacc[nt][r]);                                     \
          rs += p;                                                           \
          pb[r] = f2bf(p);                                                   \
        }                                                                    \
        lrun[nt] += rs;                                                      \
        *(short4t*)&ps[(CUR)][nt * 16 + c16][pw * 16 + g * 4] = pb;          \
      }                                                                      \
    }                                                                        \
  } else {                                                                   \
    if ((I) < NIT) { /* V(I) reg prefetch, consumed next interval */         \
      const short* vsrc = vtb + (size_t)(I) * 16384 + pw * 4096;             \
      _Pragma("unroll")                                                      \
      for (int ot = 0; ot < 4; ++ot)                                         \
        _Pragma("unroll")                                                    \
        for (int kk = 0; kk < 2; ++kk)                                       \
          vreg[(CUR)][ot * 2 + kk] = *(const bf16x8*)                        \
              &vsrc[(ot * 16 + c16) * 64 + (((kk * 4 + g) ^ (c16 & 7)) * 8)];\
    }                                                                        \
    if ((I) > 0) { /* O += V(I-1) P(I-1)^T for o-slice pw */                 \
      _Pragma("unroll")                                                      \
      for (int kk = 0; kk < 2; ++kk) {                                       \
        bf16x8 pf[4];                                                        \
        _Pragma("unroll")                                                    \
        for (int nt = 0; nt < 4; ++nt)                                       \
          pf[nt] = *(const bf16x8*)                                          \
              &ps[(CUR) ^ 1][nt * 16 + c16][kk * 32 + g * 8];                \
        _Pragma("unroll")                                                    \
        for (int ot = 0; ot < 4; ++ot) {                                     \
          bf16x8 vf = vreg[(CUR) ^ 1][ot * 2 + kk];                          \
          _Pragma("unroll")                                                  \
          for (int nt = 0; nt < 4; ++nt)                                     \
            oacc[ot][nt] = __builtin_amdgcn_mfma_f32_16x16x32_bf16(          \
                vf, pf[nt], oacc[ot][nt], 0, 0, 0);                          \
        }                                                                    \
      }                                                                      \
    }                                                                        \
  }

__global__ __launch_bounds__(512, 2) void flash_attn(
    const short* __restrict__ qg, const short* __restrict__ kt,
    const short* __restrict__ vt, float* __restrict__ out) {
  const int xg = blockIdx.x;
  const int b  = xg >> 1;
  const int n0 = (((xg & 1) << 5) + blockIdx.y) * 64;
  const int tid = threadIdx.x;
  const int w = tid >> 6, lane = tid & 63;
  const int g = lane >> 4, c16 = lane & 15;
  const bool prod = (w < 4);
  const int pw = w & 3;            // producer granule / consumer o-slice

  __shared__ short kb[2][16384];   // K dbuf: 64 keys x 256 o (64 KB)
  __shared__ short ps[2][64][72];  // P dbuf: 64 n x 64 m (18 KB)
  __shared__ float lsum[4][64];

  const short* ktb = kt + (size_t)b * N_ * O_;
  const short* vtb = vt + (size_t)b * N_ * O_;

  bf16x8 qf[4][8];                 // producers: all 64 n x 256 o
  bf16x8 vreg[2][8];               // consumers: V frag dbuf (o-slice pw)
  float lrun[4] = {0.f, 0.f, 0.f, 0.f};
  f32x4 oacc[4][4];
#pragma unroll
  for (int i = 0; i < 4; ++i)
#pragma unroll
    for (int j = 0; j < 4; ++j) oacc[i][j] = (f32x4){0.f, 0.f, 0.f, 0.f};

  if (prod) {
#pragma unroll
    for (int nt = 0; nt < 4; ++nt) {
      const short* qrow =
          qg + (size_t)(b * N_ + n0 + nt * 16 + c16) * O_ + g * 8;
#pragma unroll
      for (int ko = 0; ko < 8; ++ko)
        qf[nt][ko] = *(const bf16x8*)(qrow + ko * 32);
    }
    // prologue: K(0) granule pw -> kb[0]
    const short* src = ktb + (size_t)pw * 4096;
#pragma unroll
    for (int j = 0; j < 8; ++j)
      dma16(src + j * 512 + lane * 8, &kb[0][pw * 4096 + j * 512]);
  }
  __syncthreads();

  const int sw = (g ^ ((c16 >> 1) & 3)) * 8;   // K chunk swizzle (shorts)

  for (int ih = 0; ih < NIT / 2; ++ih) {
    PSTEP(2 * ih, 0);
    __syncthreads();
    PSTEP(2 * ih + 1, 1);
    __syncthreads();
  }
  PSTEP(NIT, 0);   // tail: consumers drain PV(NIT-1); producers idle
  __syncthreads();

  // epilogue: producers publish granule row-sums; consumers normalize+store
  if (prod) {
#pragma unroll
    for (int nt = 0; nt < 4; ++nt) {
      float v = lrun[nt];
      v += __shfl_xor(v, 16);
      v += __shfl_xor(v, 32);
      if (lane < 16) lsum[pw][nt * 16 + lane] = v;
    }
  }
  __syncthreads();
  if (!prod) {
#pragma unroll
    for (int nt = 0; nt < 4; ++nt) {
      const int nl = nt * 16 + c16;
      float l = lsum[0][nl] + lsum[1][nl] + lsum[2][nl] + lsum[3][nl];
      float li = 1.0f / l;
#pragma unroll
      for (int ot = 0; ot < 4; ++ot) {
        float* op = out + ((size_t)b * O_ + pw * 64 + ot * 16 + g * 4) * N_ +
                    n0 + nl;
#pragma unroll
        for (int r = 0; r < 4; ++r)
          op[(size_t)r * N_] = oacc[ot][nt][r] * li;
      }
    }
  }
}

// ---------------------------------------------------------------------------
extern "C" void kernel_launch(void* const* d_in, const int* in_sizes, int n_in,
                              void* d_out, int out_size, void* d_ws,
                              size_t ws_size, hipStream_t stream) {
  const float* x  = (const float*)d_in[0];
  const float* xx = (const float*)d_in[1];
  const float* Wq = (const float*)d_in[2];
  const float* Wk = (const float*)d_in[3];
  const float* Wv = (const float*)d_in[4];
  float* out = (float*)d_out;

  short* qg = (short*)d_ws;                         // 8.39 MB
  short* kt = qg + (size_t)B_ * N_ * O_;            // 8.39 MB (tiled K)
  short* vt = kt + (size_t)B_ * N_ * O_;            // 8.39 MB (tiled V)

  qkv_proj<<<dim3(N_ / 64, B_, 3), 256, 0, stream>>>(x, xx, Wq, Wk, Wv, qg,
                                                     kt, vt);
  flash_attn<<<dim3(8, 32), 512, 0, stream>>>(qg, kt, vt, out);
}

// Round 12
// 254.694 us; speedup vs baseline: 1.2638x; 1.2638x over previous
//
#include <hip/hip_runtime.h>
#include <hip/hip_bf16.h>
#include <hip/hip_cooperative_groups.h>

// CrossAttention: B=4, C=256, N=4096, OUT=256, temp=16.
// v12: ONE cooperative kernel (proj phase + grid.sync + r8 flash verbatim).
//  - Grid (8,32) x 512thr = 256 WGs = 1/CU (LDS 147KB) -> co-resident;
//    hipLaunchCooperativeKernel + grid.sync() between phases.
//  - Phase 1: WG (b,nblk) computes Q/K/V for its 64 n-rows (r8 proj math on
//    8 waves: wave w = o-slice (w&3)*64 + (w>>2)*32). W fp32 read + inline
//    bf16 cvt (temp folded into Wq). LDS staging/assembly reuses kb/vb.
//  - Phase 2: r8 flash verbatim (4P+4C wave specialization, K/V dma16 dbuf,
//    XCD-pinned b = x>>1, in-kernel normalize). VGPR ~120, no spill (r11's
//    regression was vreg-induced scratch spill: WRITE 28->69MB).
//  - Single dispatch makes residual = total - dispatch, finally measurable.
// Workspace: qg 8.4MB + kt 8.4MB + vt 8.4MB.

namespace cg = cooperative_groups;

typedef __attribute__((ext_vector_type(8))) short bf16x8;
typedef __attribute__((ext_vector_type(4))) float f32x4;
typedef __attribute__((ext_vector_type(4))) short short4t;

constexpr int B_ = 4;
constexpr int C_ = 256;
constexpr int N_ = 4096;
constexpr int O_ = 256;
constexpr float INV_TEMP = 1.0f / 16.0f;
constexpr int NIT = 64;   // 64-key intervals (all 4096 keys)

__device__ __forceinline__ short f2bf(float f) {
  union { float f; unsigned u; } v; v.f = f;
  unsigned r = v.u + 0x7fffu + ((v.u >> 16) & 1u);   // RNE
  return (short)(r >> 16);
}

// async global->LDS DMA: lane i reads g + i*16B, lands at ldsbase + i*16B.
__device__ __forceinline__ void dma16(const void* g, void* l) {
  __builtin_amdgcn_global_load_lds(
      (const __attribute__((address_space(1))) unsigned int*)g,
      (__attribute__((address_space(3))) unsigned int*)l, 16, 0, 0);
}

// 32-o x 64-n GEMM slice per wave; W fp32 + inline cvt. swap=1: D rows = m.
__device__ __forceinline__ void proj_gemm(
    const float* __restrict__ Wm, float ws, int swap, const short (*xs)[264],
    int W4, int oh, int g, int c16, f32x4* a) {
#pragma unroll
  for (int i = 0; i < 8; ++i) a[i] = (f32x4){0.f, 0.f, 0.f, 0.f};
#pragma unroll
  for (int ko = 0; ko < 8; ++ko) {
    bf16x8 wfr[2], xfr[4];
#pragma unroll
    for (int otl = 0; otl < 2; ++otl) {
      const float* wp = Wm +
          (size_t)(W4 * 64 + (oh * 2 + otl) * 16 + c16) * C_ + ko * 32 + g * 8;
      float4 f0 = *(const float4*)wp;
      float4 f1 = *(const float4*)(wp + 4);
      bf16x8 t;
      t[0] = f2bf(f0.x * ws); t[1] = f2bf(f0.y * ws);
      t[2] = f2bf(f0.z * ws); t[3] = f2bf(f0.w * ws);
      t[4] = f2bf(f1.x * ws); t[5] = f2bf(f1.y * ws);
      t[6] = f2bf(f1.z * ws); t[7] = f2bf(f1.w * ws);
      wfr[otl] = t;
    }
#pragma unroll
    for (int nt = 0; nt < 4; ++nt)
      xfr[nt] = *(const bf16x8*)&xs[nt * 16 + c16][ko * 32 + g * 8];
    if (!swap) {
#pragma unroll
      for (int otl = 0; otl < 2; ++otl)
#pragma unroll
        for (int nt = 0; nt < 4; ++nt)
          a[otl * 4 + nt] = __builtin_amdgcn_mfma_f32_16x16x32_bf16(
              wfr[otl], xfr[nt], a[otl * 4 + nt], 0, 0, 0);
    } else {
#pragma unroll
      for (int mt = 0; mt < 4; ++mt)
#pragma unroll
        for (int otl = 0; otl < 2; ++otl)
          a[mt * 2 + otl] = __builtin_amdgcn_mfma_f32_16x16x32_bf16(
              xfr[mt], wfr[otl], a[mt * 2 + otl], 0, 0, 0);
    }
  }
}

// ---------------------------------------------------------------------------
__global__ __launch_bounds__(512, 2) void fused(
    const float* __restrict__ x, const float* __restrict__ xx,
    const float* __restrict__ Wq, const float* __restrict__ Wk,
    const float* __restrict__ Wv,
    short* __restrict__ qg, short* __restrict__ kt, short* __restrict__ vt,
    float* __restrict__ out) {
  const int xg = blockIdx.x;
  const int b  = xg >> 1;
  const int n0 = (((xg & 1) << 5) + blockIdx.y) * 64;
  const int tid = threadIdx.x;
  const int w = tid >> 6, lane = tid & 63;
  const int g = lane >> 4, c16 = lane & 15;

  __shared__ short kb[2][16384];   // phase1: xs staging | phase2: K dbuf
  __shared__ short vb[2][16384];   // phase1: obuf       | phase2: V dbuf
  __shared__ short ps[2][64][72];
  __shared__ float lsum[4][64];

  // =================== PHASE 1: projections for this (b, n0) ==============
  {
    short (*xs)[264] = (short(*)[264])&kb[0][0];   // 64 x 264 (33.8 KB)
    short* obuf = &vb[0][0];                       // 32 KB assembly
    const int W4 = w & 3, oh = w >> 2;
    f32x4 a[8];

    {  // stage x tile
      const int n = tid & 63, cq = tid >> 6;
      const float* sp = x + (size_t)b * C_ * N_ + n0 + n;
#pragma unroll
      for (int rep = 0; rep < 8; ++rep) {
        int c = rep * 32 + cq * 4;
        short4t s4;
#pragma unroll
        for (int j = 0; j < 4; ++j) s4[j] = f2bf(sp[(size_t)(c + j) * N_]);
        *(short4t*)&xs[n][c] = s4;
      }
    }
    __syncthreads();

    // ---- Q ----
    proj_gemm(Wq, INV_TEMP, 0, xs, W4, oh, g, c16, a);
    __syncthreads();   // xs(x) reads done
    {  // assemble Q -> obuf; restage xx -> xs (disjoint regions)
#pragma unroll
      for (int otl = 0; otl < 2; ++otl)
#pragma unroll
        for (int nt = 0; nt < 4; ++nt) {
          int f = (nt * 16 + c16) * 256 + W4 * 64 + (oh * 2 + otl) * 16 + g * 4;
          f32x4 v = a[otl * 4 + nt];
          short4t s;
          s[0] = f2bf(v[0]); s[1] = f2bf(v[1]);
          s[2] = f2bf(v[2]); s[3] = f2bf(v[3]);
          *(short4t*)&obuf[f] = s;
        }
      const int n = tid & 63, cq = tid >> 6;
      const float* sp = xx + (size_t)b * C_ * N_ + n0 + n;
#pragma unroll
      for (int rep = 0; rep < 8; ++rep) {
        int c = rep * 32 + cq * 4;
        short4t s4;
#pragma unroll
        for (int j = 0; j < 4; ++j) s4[j] = f2bf(sp[(size_t)(c + j) * N_]);
        *(short4t*)&xs[n][c] = s4;
      }
    }
    __syncthreads();
    {  // blast Q; K GEMM (reads xs=xx)
      const uint4* s4 = (const uint4*)obuf;
      uint4* d4 = (uint4*)(qg + ((size_t)b * N_ + n0) * O_);
#pragma unroll
      for (int j = 0; j < 4; ++j) d4[j * 512 + tid] = s4[j * 512 + tid];
      proj_gemm(Wk, 1.0f, 0, xs, W4, oh, g, c16, a);
    }
    __syncthreads();   // Q-blast obuf reads done
    {  // assemble K -> obuf
#pragma unroll
      for (int otl = 0; otl < 2; ++otl)
#pragma unroll
        for (int nt = 0; nt < 4; ++nt) {
          int koo = W4 * 2 + oh;
          int pos = ((otl * 2 + (g >> 1)) ^ ((c16 >> 1) & 3));
          int f = nt * 4096 + koo * 512 + c16 * 32 + pos * 8 + (g & 1) * 4;
          f32x4 v = a[otl * 4 + nt];
          short4t s;
          s[0] = f2bf(v[0]); s[1] = f2bf(v[1]);
          s[2] = f2bf(v[2]); s[3] = f2bf(v[3]);
          *(short4t*)&obuf[f] = s;
        }
    }
    __syncthreads();
    {  // blast K; V GEMM (xs still xx)
      const uint4* s4 = (const uint4*)obuf;
      uint4* d4 = (uint4*)(kt + (size_t)(b * 256 + (n0 >> 4)) * 4096);
#pragma unroll
      for (int j = 0; j < 4; ++j) d4[j * 512 + tid] = s4[j * 512 + tid];
      proj_gemm(Wv, 1.0f, 1, xs, W4, oh, g, c16, a);
    }
    __syncthreads();   // K-blast obuf reads done
    {  // assemble V -> obuf (a[mt*2+otl]: rows m, cols o)
#pragma unroll
      for (int mt = 0; mt < 4; ++mt)
#pragma unroll
        for (int otl = 0; otl < 2; ++otl) {
          int o = W4 * 64 + (oh * 2 + otl) * 16 + c16;
          int pos = (mt * 2 + (g >> 1)) ^ (o & 7);
          int f = o * 64 + pos * 8 + (g & 1) * 4;
          f32x4 v = a[mt * 2 + otl];
          short4t s;
          s[0] = f2bf(v[0]); s[1] = f2bf(v[1]);
          s[2] = f2bf(v[2]); s[3] = f2bf(v[3]);
          *(short4t*)&obuf[f] = s;
        }
    }
    __syncthreads();
    {  // blast V
      const uint4* s4 = (const uint4*)obuf;
      uint4* d4 = (uint4*)(vt + (size_t)(b * 64 + (n0 >> 6)) * 16384);
#pragma unroll
      for (int j = 0; j < 4; ++j) d4[j * 512 + tid] = s4[j * 512 + tid];
    }
  }

  cg::this_grid().sync();   // all Q/K/V global; device-scope fence

  // =================== PHASE 2: flash attention (r8 verbatim) =============
  const bool prod = (w < 4);
  const int pw = w & 3;

  const short* ktb = kt + (size_t)b * N_ * O_;
  const short* vtb = vt + (size_t)b * N_ * O_;

  bf16x8 qf[4][8];
  float lrun[4] = {0.f, 0.f, 0.f, 0.f};
  f32x4 oacc[4][4];
#pragma unroll
  for (int i = 0; i < 4; ++i)
#pragma unroll
    for (int j = 0; j < 4; ++j) oacc[i][j] = (f32x4){0.f, 0.f, 0.f, 0.f};

  if (prod) {
#pragma unroll
    for (int nt = 0; nt < 4; ++nt) {
      const short* qrow =
          qg + (size_t)(b * N_ + n0 + nt * 16 + c16) * O_ + g * 8;
#pragma unroll
      for (int ko = 0; ko < 8; ++ko)
        qf[nt][ko] = *(const bf16x8*)(qrow + ko * 32);
    }
    const short* src = ktb + (size_t)pw * 4096;
#pragma unroll
    for (int j = 0; j < 8; ++j)
      dma16(src + j * 512 + lane * 8, &kb[0][pw * 4096 + j * 512]);
  }
  __syncthreads();

  const int sw = (g ^ ((c16 >> 1) & 3)) * 8;   // K chunk swizzle (shorts)

  for (int i = 0; i <= NIT; ++i) {
    if (prod) {
      if (i < NIT) {
        if (i + 1 < NIT) {  // prefetch K(i+1) granule pw
          const short* src = ktb + (size_t)(4 * (i + 1) + pw) * 4096;
          short* dst = &kb[(i + 1) & 1][pw * 4096];
#pragma unroll
          for (int j = 0; j < 8; ++j)
            dma16(src + j * 512 + lane * 8, dst + j * 512);
        }
        // S^T = K Q^T for granule pw (rows m), all 64 n
        const short* ksl = &kb[i & 1][pw * 4096];
        f32x4 sacc[4];
#pragma unroll
        for (int nt = 0; nt < 4; ++nt) sacc[nt] = (f32x4){0.f, 0.f, 0.f, 0.f};
#pragma unroll
        for (int ko = 0; ko < 8; ++ko) {
          bf16x8 kf = *(const bf16x8*)&ksl[(ko * 16 + c16) * 32 + sw];
#pragma unroll
          for (int nt = 0; nt < 4; ++nt)
            sacc[nt] = __builtin_amdgcn_mfma_f32_16x16x32_bf16(
                kf, qf[nt][ko], sacc[nt], 0, 0, 0);
        }
        // p = exp(s) (no max subtraction: |s| <= ~2.5 by construction)
#pragma unroll
        for (int nt = 0; nt < 4; ++nt) {
          short4t pb;
          float rs = 0.f;
#pragma unroll
          for (int r = 0; r < 4; ++r) {
            float p = __expf(sacc[nt][r]);
            rs += p;
            pb[r] = f2bf(p);
          }
          lrun[nt] += rs;
          *(short4t*)&ps[i & 1][nt * 16 + c16][pw * 16 + g * 4] = pb;
        }
      }
    } else {
      if (i < NIT) {  // prefetch V(i) o-slice pw
        const short* src = vtb + (size_t)i * 16384 + pw * 4096;
        short* dst = &vb[i & 1][pw * 4096];
#pragma unroll
        for (int j = 0; j < 8; ++j)
          dma16(src + j * 512 + lane * 8, dst + j * 512);
      }
      if (i > 0) {  // O += V(i-1) P(i-1)^T for o-slice pw
        const int pb_ = (i - 1) & 1;
#pragma unroll
        for (int kk = 0; kk < 2; ++kk) {
          bf16x8 pf[4];
#pragma unroll
          for (int nt = 0; nt < 4; ++nt)
            pf[nt] = *(const bf16x8*)&ps[pb_][nt * 16 + c16][kk * 32 + g * 8];
#pragma unroll
          for (int ot = 0; ot < 4; ++ot) {
            int pos = (kk * 4 + g) ^ (c16 & 7);
            bf16x8 vf = *(const bf16x8*)
                &vb[pb_][(pw * 64 + ot * 16 + c16) * 64 + pos * 8];
#pragma unroll
            for (int nt = 0; nt < 4; ++nt)
              oacc[ot][nt] = __builtin_amdgcn_mfma_f32_16x16x32_bf16(
                  vf, pf[nt], oacc[ot][nt], 0, 0, 0);
          }
        }
      }
    }
    __syncthreads();
  }

  // epilogue: producers publish granule row-sums; consumers normalize+store
  if (prod) {
#pragma unroll
    for (int nt = 0; nt < 4; ++nt) {
      float v = lrun[nt];
      v += __shfl_xor(v, 16);
      v += __shfl_xor(v, 32);
      if (lane < 16) lsum[pw][nt * 16 + lane] = v;
    }
  }
  __syncthreads();
  if (!prod) {
#pragma unroll
    for (int nt = 0; nt < 4; ++nt) {
      const int nl = nt * 16 + c16;
      float l = lsum[0][nl] + lsum[1][nl] + lsum[2][nl] + lsum[3][nl];
      float li = 1.0f / l;
#pragma unroll
      for (int ot = 0; ot < 4; ++ot) {
        float* op = out + ((size_t)b * O_ + pw * 64 + ot * 16 + g * 4) * N_ +
                    n0 + nl;
#pragma unroll
        for (int r = 0; r < 4; ++r)
          op[(size_t)r * N_] = oacc[ot][nt][r] * li;
      }
    }
  }
}

// ---------------------------------------------------------------------------
extern "C" void kernel_launch(void* const* d_in, const int* in_sizes, int n_in,
                              void* d_out, int out_size, void* d_ws,
                              size_t ws_size, hipStream_t stream) {
  const float* x  = (const float*)d_in[0];
  const float* xx = (const float*)d_in[1];
  const float* Wq = (const float*)d_in[2];
  const float* Wk = (const float*)d_in[3];
  const float* Wv = (const float*)d_in[4];
  float* out = (float*)d_out;

  short* qg = (short*)d_ws;                         // 8.39 MB
  short* kt = qg + (size_t)B_ * N_ * O_;            // 8.39 MB (tiled K)
  short* vt = kt + (size_t)B_ * N_ * O_;            // 8.39 MB (tiled V)

  void* args[] = {(void*)&x, (void*)&xx, (void*)&Wq, (void*)&Wk, (void*)&Wv,
                  (void*)&qg, (void*)&kt, (void*)&vt, (void*)&out};
  hipLaunchCooperativeKernel((const void*)fused, dim3(8, 32), dim3(512, 1, 1),
                             args, 0, stream);
}